// Round 7
// baseline (174.514 us; speedup 1.0000x reference)
//
#include <hip/hip_runtime.h>
#include <hip/hip_fp16.h>
#include <float.h>

#define NEG 0.2f
#define NPART 16
#define PAD 32   // csr row stride = 128B (one line); deg ~ Poisson(6), P(>=32) ~ 1e-15

typedef _Float16 half8 __attribute__((ext_vector_type(8)));
typedef float f32x4 __attribute__((ext_vector_type(4)));

__device__ __forceinline__ float lrelu(float x){ return x > 0.f ? x : NEG * x; }
__device__ __forceinline__ float elu1(float x){ return x > 0.f ? x : (__expf(x) - 1.f); }

// ---- Padded-CSR build + per-graph node counts (fused) ----
// cur[] pre-zeroed; after this pass cur[node] == in-degree
__global__ void k_scat(const int* __restrict__ ei, const int* __restrict__ batch,
                       int* __restrict__ cur, int* __restrict__ csr_src,
                       float* __restrict__ gcnt, int N, int E){
  __shared__ float gc[128];
  int tid = threadIdx.x;
  bool doh = blockIdx.x < 256;                         // block-uniform
  if (doh && tid < 128) gc[tid] = 0.f;
  __syncthreads();
  int idx = blockIdx.x * 256 + tid;
  int gstr = gridDim.x * 256;
  for (int e = idx; e < E; e += gstr){
    int s = ei[e], d = ei[E + e];
    int pos = atomicAdd(cur + d, 1);
    if (pos < PAD) csr_src[(size_t)d * PAD + pos] = s; // guard impossible overflow
  }
  if (doh){
    for (int n = idx; n < N; n += 256 * 256)
      atomicAdd(&gc[batch[n]], 1.f);
    __syncthreads();
    if (tid < 128 && gc[tid] != 0.f) atomicAdd(gcnt + tid, gc[tid]);
  }
}

// ---- Fused layer 1: edge accumulation (linearity trick) + out1 + h2 + L2 logits
// phase 1: 8 lanes/node; first-round loads hoisted above the PQ preamble.
// phase 2: out1 f16 in LDS [32][136]; h2 = out1 @ W2 via 4x mfma_f32_16x16x32_f16
// Output row h2x[node]: 128B line = {32 halfs h2 | als2 float | pad}. Co-locating
// als2 with h2 means gat2's ex-read warms the SAME line its h2-gathers hit (R7).
// NOTE: min-waves 6 (not 8): 8 forces a 64-VGPR budget -> scratch spill (R15).
__global__ void __launch_bounds__(256, 6)
k_layer1(const int* __restrict__ degp, const int* __restrict__ csr_src,
         const float* __restrict__ x, const float* __restrict__ W1,
         const float* __restrict__ as1, const float* __restrict__ ad1,
         const float* __restrict__ b1, const float* __restrict__ W2,
         const float* __restrict__ as2, const float* __restrict__ ad2,
         __half* __restrict__ h2x, float* __restrict__ ald2, int N){
  __shared__ float PQ[2][16];                          // [which][k*4+h]
  __shared__ __align__(16) float xa[32][20];           // per-node {acc[16], rs[4]}
  __shared__ __align__(16) _Float16 out1sh[32][136];   // pad 8 halfs: 272B row -> 2-way on b128
  __shared__ __align__(16) float h2sh[32][36];         // f32 h2 tile (pad for b128 align)
  __shared__ float als_s[32], ald_s[32];               // staged L2-logit outputs
  int tid = threadIdx.x;
  const float4* x4 = (const float4*)x;

  // ---- speculative first-round loads (before PQ compute + barrier) ----
  int g1 = tid >> 3, l = tid & 7;
  int node1 = blockIdx.x * 32 + g1;
  int nd = node1 < N ? node1 : N - 1;
  int deg = degp[nd];                                  // load A
  size_t r0 = (size_t)nd * PAD;
  int s_pre = csr_src[r0 + l];                         // load B (indep of A)
  int total = (node1 < N) ? deg + 1 : 0;
  int s0 = (l < deg) ? s_pre : nd;                     // sanitize poison beyond deg
  float4 xv0 = x4[s0];                                 // gather (depth 2)
  float4 xn = x4[nd];

  if (tid < 32){
    int which = tid >> 4, kh = tid & 15, k = kh >> 2, h = kh & 3;
    const float* a = which ? ad1 : as1;
    float s = 0.f;
    #pragma unroll 8
    for (int c = 0; c < 32; c++) s += W1[k*128 + h*32 + c] * a[h*32 + c];
    PQ[which][kh] = s;
  }
  __syncthreads();

  // ---- phase 1: 8 lanes per node ----
  {
    float P[16], Q[16];
    #pragma unroll
    for (int i = 0; i < 16; i++){ P[i] = PQ[0][i]; Q[i] = PQ[1][i]; }
    float ald0 = xn.x*Q[0] + xn.y*Q[4] + xn.z*Q[8]  + xn.w*Q[12];
    float ald1_ = xn.x*Q[1] + xn.y*Q[5] + xn.z*Q[9]  + xn.w*Q[13];
    float ald2_ = xn.x*Q[2] + xn.y*Q[6] + xn.z*Q[10] + xn.w*Q[14];
    float ald3 = xn.x*Q[3] + xn.y*Q[7] + xn.z*Q[11] + xn.w*Q[15];
    float acc[16];
    #pragma unroll
    for (int i = 0; i < 16; i++) acc[i] = 0.f;
    float ss[4] = {0.f, 0.f, 0.f, 0.f};
    if (l < total){                                    // first round: preloaded
      float4 xv = xv0;
      float a0 = xv.x*P[0] + xv.y*P[4] + xv.z*P[8]  + xv.w*P[12];
      float a1 = xv.x*P[1] + xv.y*P[5] + xv.z*P[9]  + xv.w*P[13];
      float a2 = xv.x*P[2] + xv.y*P[6] + xv.z*P[10] + xv.w*P[14];
      float a3 = xv.x*P[3] + xv.y*P[7] + xv.z*P[11] + xv.w*P[15];
      float e0 = __expf(lrelu(a0 + ald0));
      float e1 = __expf(lrelu(a1 + ald1_));
      float e2 = __expf(lrelu(a2 + ald2_));
      float e3 = __expf(lrelu(a3 + ald3));
      ss[0] += e0; ss[1] += e1; ss[2] += e2; ss[3] += e3;
      acc[0]  += e0*xv.x; acc[1]  += e0*xv.y; acc[2]  += e0*xv.z; acc[3]  += e0*xv.w;
      acc[4]  += e1*xv.x; acc[5]  += e1*xv.y; acc[6]  += e1*xv.z; acc[7]  += e1*xv.w;
      acc[8]  += e2*xv.x; acc[9]  += e2*xv.y; acc[10] += e2*xv.z; acc[11] += e2*xv.w;
      acc[12] += e3*xv.x; acc[13] += e3*xv.y; acc[14] += e3*xv.z; acc[15] += e3*xv.w;
    }
    for (int t = l + 8; t < total; t += 8){            // rare (P(deg>=8) ~ 0.26)
      int s = (t < deg) ? csr_src[r0 + t] : nd;
      float4 xv = x4[s];
      float a0 = xv.x*P[0] + xv.y*P[4] + xv.z*P[8]  + xv.w*P[12];
      float a1 = xv.x*P[1] + xv.y*P[5] + xv.z*P[9]  + xv.w*P[13];
      float a2 = xv.x*P[2] + xv.y*P[6] + xv.z*P[10] + xv.w*P[14];
      float a3 = xv.x*P[3] + xv.y*P[7] + xv.z*P[11] + xv.w*P[15];
      float e0 = __expf(lrelu(a0 + ald0));
      float e1 = __expf(lrelu(a1 + ald1_));
      float e2 = __expf(lrelu(a2 + ald2_));
      float e3 = __expf(lrelu(a3 + ald3));
      ss[0] += e0; ss[1] += e1; ss[2] += e2; ss[3] += e3;
      acc[0]  += e0*xv.x; acc[1]  += e0*xv.y; acc[2]  += e0*xv.z; acc[3]  += e0*xv.w;
      acc[4]  += e1*xv.x; acc[5]  += e1*xv.y; acc[6]  += e1*xv.z; acc[7]  += e1*xv.w;
      acc[8]  += e2*xv.x; acc[9]  += e2*xv.y; acc[10] += e2*xv.z; acc[11] += e2*xv.w;
      acc[12] += e3*xv.x; acc[13] += e3*xv.y; acc[14] += e3*xv.z; acc[15] += e3*xv.w;
    }
    #pragma unroll
    for (int m = 4; m >= 1; m >>= 1){
      #pragma unroll
      for (int i = 0; i < 16; i++) acc[i] += __shfl_xor(acc[i], m, 8);
      #pragma unroll
      for (int i = 0; i < 4; i++)  ss[i]  += __shfl_xor(ss[i], m, 8);
    }
    if (l == 0){
      float* o = xa[g1];
      *(float4*)(o)      = make_float4(acc[0],  acc[1],  acc[2],  acc[3]);
      *(float4*)(o + 4)  = make_float4(acc[4],  acc[5],  acc[6],  acc[7]);
      *(float4*)(o + 8)  = make_float4(acc[8],  acc[9],  acc[10], acc[11]);
      *(float4*)(o + 12) = make_float4(acc[12], acc[13], acc[14], acc[15]);
      *(float4*)(o + 16) = make_float4(ss[0], ss[1], ss[2], ss[3]);
    }
  }
  __syncthreads();
  // cooperative reciprocal: one IEEE div per (node, head) instead of 16x per thread
  if (tid < 128) xa[tid >> 2][16 + (tid & 3)] = 1.f / xa[tid >> 2][16 + (tid & 3)];
  __builtin_amdgcn_sched_barrier(0);   // keep phase-2 weight loads below phase 1

  // ---- phase-2 constants: live range starts after phase 1 (no spill) ----
  int wv = tid >> 6, lane = tid & 63;
  int wm = wv >> 1, wn = wv & 1;                      // wave's 16x16 output tile
  int lrow = lane & 15, lk8 = lane >> 4;              // frag row/col + k-octet
  // B fragments: W2[k][n], lane holds k = t*32 + lk8*8 + j, n = wn*16 + lrow
  half8 bf[4];
  #pragma unroll
  for (int t = 0; t < 4; t++){
    #pragma unroll
    for (int j = 0; j < 8; j++)
      bf[t][j] = (_Float16)W2[(t*32 + lk8*8 + j)*32 + wn*16 + lrow];
  }
  // out1 weights: thread owns channel c128 for 16 nodes
  int c128 = ((wv & 1) << 6) | lane;                  // 0..127
  int gbase = (wv >> 1) << 4;                         // nodes gbase..gbase+15
  int hh = c128 >> 5;                                 // head of this channel
  float w1c0 = W1[c128], w1c1 = W1[128 + c128];
  float w1c2 = W1[256 + c128], w1c3 = W1[384 + c128];
  float b1c = b1[c128];
  __syncthreads();                                    // rcp fixup visible

  // ---- phase 2a: out1 = elu((xa . W1) * rs + b1) for all 32 nodes -> LDS f16 ----
  #pragma unroll
  for (int i = 0; i < 16; i++){
    int g = gbase + i;
    const float* xg = xa[g];
    float4 xv = *(const float4*)(xg + hh*4);          // broadcast LDS
    float rs = xg[16 + hh];
    float o = elu1((xv.x*w1c0 + xv.y*w1c1 + xv.z*w1c2 + xv.w*w1c3) * rs + b1c);
    out1sh[g][c128] = (_Float16)o;
  }
  __syncthreads();

  // ---- phase 2b: h2 = out1 @ W2 via MFMA (M=32, N=32, K=128) ----
  {
    f32x4 acc2 = {0.f, 0.f, 0.f, 0.f};
    #pragma unroll
    for (int t = 0; t < 4; t++){
      half8 af = *(const half8*)(&out1sh[wm*16 + lrow][t*32 + lk8*8]);
      acc2 = __builtin_amdgcn_mfma_f32_16x16x32_f16(af, bf[t], acc2, 0, 0, 0);
    }
    // C/D layout: col = lane&15, row = (lane>>4)*4 + i
    #pragma unroll
    for (int i = 0; i < 4; i++)
      h2sh[wm*16 + lk8*4 + i][wn*16 + lrow] = acc2[i];
  }
  __syncthreads();

  // ---- epilogue: h2x f16 store + L2 logits (8 lanes per node) ----
  {
    int g = tid >> 3, q = tid & 7;                    // node g, channels 4q..4q+3
    int node = blockIdx.x * 32 + g;
    float4 hv = *(const float4*)(&h2sh[g][q*4]);
    if (node < N){
      __half2 pa = __floats2half2_rn(hv.x, hv.y);
      __half2 pb = __floats2half2_rn(hv.z, hv.w);
      __half2* dst = (__half2*)(h2x + (size_t)node*64 + q*4);
      dst[0] = pa; dst[1] = pb;
    }
    float4 sa = *(const float4*)(as2 + q*4);
    float4 da = *(const float4*)(ad2 + q*4);
    float ps = hv.x*sa.x + hv.y*sa.y + hv.z*sa.z + hv.w*sa.w;
    float pd = hv.x*da.x + hv.y*da.y + hv.z*da.z + hv.w*da.w;
    #pragma unroll
    for (int m = 4; m >= 1; m >>= 1){
      ps += __shfl_xor(ps, m, 8);
      pd += __shfl_xor(pd, m, 8);
    }
    if (q == 0){ als_s[g] = ps; ald_s[g] = pd; }      // stage in LDS
  }
  __syncthreads();
  if (tid < 32){
    int node = blockIdx.x * 32 + tid;
    if (node < N){
      ald2[node] = ald_s[tid];
      *(float*)(h2x + (size_t)node*64 + 32) = als_s[tid];  // als2 into the h2 line
    }
  }
}

// ---- Layer 2 gather + pool partials: co-located h2x rows ----
// block 256 = 8 nodes x 32 lanes; c2 = lane&15 -> channels 2c2,2c2+1;
// sub = lane>>4 picks which edge of the pair. Row h2x[s] is ONE 128B line
// holding {h2 halfs, als float}: the ex-read (als) warms the exact line the
// h2-gathers hit -> those become L1 hits; random line touches per edge 2 -> 1.
// Full 8-edge rounds, no guards (lanes past total: ex=0, s=node, safe row).
// R5: global atomics exonerated. R17: NO per-block device fences (935us).
__global__ void __launch_bounds__(256)
k_gat2(const int* __restrict__ degp, const int* __restrict__ csr_src,
       const __half* __restrict__ h2x, const float* __restrict__ ald2,
       const float* __restrict__ b2, const int* __restrict__ batch,
       float* __restrict__ gsum_part, int N){
  int tid = threadIdx.x;
  int node = blockIdx.x * 8 + (tid >> 5);
  if (node >= N) return;
  int lane = tid & 31;
  int c2 = lane & 15;                                  // channel pair: 2c2, 2c2+1
  int sub = lane >> 4;                                 // which edge of the pair
  int deg = degp[node];
  size_t r0 = (size_t)node * PAD;
  int total = deg + 1;
  float ald = ald2[node];

  float ssum = 0.f;
  float f0 = 0.f, f1 = 0.f, f2 = 0.f, f3 = 0.f;
  for (int base = 0; base < total; base += 32){
    int t = base + lane;
    int s = (t < deg) ? csr_src[r0 + t] : node;
    float als = *(const float*)(h2x + (size_t)s*64 + 32);   // warms the h2 line
    float ex = (t < total) ? __expf(lrelu(als + ald)) : 0.f;
    ssum += ex;
    int lim = min(32, total - base);
    for (int jj = 0; jj < lim; jj += 8){               // full 8-edge rounds, no guards
      int ja = jj + sub,     jb = jj + 2 + sub;        // all indices <= 31 (jj <= 24)
      int jc = jj + 4 + sub, jd = jj + 6 + sub;
      float ea = __shfl(ex, ja, 32); int sa = __shfl(s, ja, 32);
      float eb = __shfl(ex, jb, 32); int sb = __shfl(s, jb, 32);
      float ec = __shfl(ex, jc, 32); int sc = __shfl(s, jc, 32);
      float ed = __shfl(ex, jd, 32); int sd = __shfl(s, jd, 32);
      float2 va = __half22float2(*(const __half2*)(h2x + (size_t)sa*64 + 2*c2));
      float2 vb = __half22float2(*(const __half2*)(h2x + (size_t)sb*64 + 2*c2));
      float2 vc = __half22float2(*(const __half2*)(h2x + (size_t)sc*64 + 2*c2));
      float2 vd = __half22float2(*(const __half2*)(h2x + (size_t)sd*64 + 2*c2));
      f0 += ea*va.x + eb*vb.x;
      f1 += ea*va.y + eb*vb.y;
      f2 += ec*vc.x + ed*vd.x;
      f3 += ec*vc.y + ed*vd.y;
    }
  }
  float fx = f0 + f2, fy = f1 + f3;
  fx += __shfl_xor(fx, 16, 32);                        // combine sub halves
  fy += __shfl_xor(fy, 16, 32);
  #pragma unroll
  for (int m = 16; m >= 1; m >>= 1) ssum += __shfl_xor(ssum, m, 32);
  // lane -> channel 2*c2+sub: each of 32 lanes writes exactly one channel
  float fc = sub ? fy : fx;
  int ch = 2*c2 + sub;
  float v = elu1(fc / ssum + b2[ch]);
  int b = batch[node];
  atomicAdd(gsum_part + ((blockIdx.x & (NPART-1)) << 12) + b*32 + ch, v);
}

// ---- MLP head: reduce partials + divide + 2-layer MLP ----
__global__ void k_head(const float* __restrict__ gsum_part, const float* __restrict__ gcnt,
                       const float* __restrict__ Wc1, const float* __restrict__ bc1,
                       const float* __restrict__ Wc2, const float* __restrict__ bc2,
                       float* __restrict__ out){
  int g = blockIdx.x, tid = threadIdx.x;
  __shared__ float gl[32];
  if (tid < 32){
    float s = 0.f;
    #pragma unroll
    for (int p = 0; p < NPART; p++) s += gsum_part[(p << 12) + g*32 + tid];
    float cnt = gcnt[g];
    cnt = cnt > 1.f ? cnt : 1.f;
    gl[tid] = s / cnt;
  }
  __syncthreads();
  if (tid < 32){
    float z = bc1[tid];
    #pragma unroll 8
    for (int c2 = 0; c2 < 32; c2++) z += gl[c2] * Wc1[c2*32 + tid];
    z = z > 0.f ? z : 0.f;
    float r = z * Wc2[tid];
    #pragma unroll
    for (int m = 16; m >= 1; m >>= 1) r += __shfl_xor(r, m, 32);
    if (tid == 0) out[g] = 1.f / (1.f + expf(-(r + bc2[0])));
  }
}

extern "C" void kernel_launch(void* const* d_in, const int* in_sizes, int n_in,
                              void* d_out, int out_size, void* d_ws, size_t ws_size,
                              hipStream_t stream){
  const float* x   = (const float*)d_in[0];
  const int*   ei  = (const int*)d_in[1];
  const int*   bat = (const int*)d_in[2];
  const float* W1  = (const float*)d_in[3];
  const float* as1 = (const float*)d_in[4];
  const float* ad1 = (const float*)d_in[5];
  const float* b1  = (const float*)d_in[6];
  const float* W2  = (const float*)d_in[7];
  const float* as2 = (const float*)d_in[8];
  const float* ad2 = (const float*)d_in[9];
  const float* b2  = (const float*)d_in[10];
  const float* Wc1 = (const float*)d_in[11];
  const float* bc1 = (const float*)d_in[12];
  const float* Wc2 = (const float*)d_in[13];
  const float* bc2 = (const float*)d_in[14];
  float* out = (float*)d_out;

  const int N = in_sizes[2];
  const int E = in_sizes[1] / 2;

  float* ws = (float*)d_ws;
  size_t off = 0;
  // zero-init region (single memset): cur + gsum_part + gcnt
  int* cur    = (int*)ws;           off += (size_t)N;        // becomes deg after k_scat
  float* gsum_part = ws + off;      off += (size_t)NPART * 4096;
  float* gcnt = ws + off;           off += 128;
  const size_t zero_elems = off;
  __half* h2x = (__half*)(ws + off); off += (size_t)N * 32;  // N rows x 128B (h2 + als)
  float* ald2 = ws + off;           off += (size_t)N;
  int* csr_src= (int*)(ws + off);   off += (size_t)N * PAD;  // 128B-aligned rows

  hipMemsetAsync(d_ws, 0, zero_elems * sizeof(float), stream);

  // padded-CSR build + gcnt histogram (fused, single edge pass)
  k_scat<<<(E + 255) / 256, 256, 0, stream>>>(ei, bat, cur, csr_src, gcnt, N, E);

  // fused layer 1 (+ h2x rows + layer-2 logits)
  k_layer1<<<(N + 31) / 32, 256, 0, stream>>>(cur, csr_src, x, W1, as1, ad1, b1,
                                              W2, as2, ad2, h2x, ald2, N);

  // layer 2 gather + fused pool partials
  k_gat2<<<(N + 7) / 8, 256, 0, stream>>>(cur, csr_src, h2x, ald2, b2,
                                          bat, gsum_part, N);

  // head (reduces partials)
  k_head<<<128, 64, 0, stream>>>(gsum_part, gcnt, Wc1, bc1, Wc2, bc2, out);
}

// Round 9
// 169.983 us; speedup vs baseline: 1.0267x; 1.0267x over previous
//
#include <hip/hip_runtime.h>
#include <hip/hip_fp16.h>
#include <float.h>

#define NEG 0.2f
#define NPART 16
#define PAD 32   // csr row stride = 128B (one line); deg ~ Poisson(6), P(>=32) ~ 1e-15

typedef _Float16 half8 __attribute__((ext_vector_type(8)));
typedef float f32x4 __attribute__((ext_vector_type(4)));

__device__ __forceinline__ float lrelu(float x){ return x > 0.f ? x : NEG * x; }
__device__ __forceinline__ float elu1(float x){ return x > 0.f ? x : (__expf(x) - 1.f); }

// ---- Padded-CSR build + per-graph node counts (fused) ----
// cur[] pre-zeroed; after this pass cur[node] == in-degree
__global__ void k_scat(const int* __restrict__ ei, const int* __restrict__ batch,
                       int* __restrict__ cur, int* __restrict__ csr_src,
                       float* __restrict__ gcnt, int N, int E){
  __shared__ float gc[128];
  int tid = threadIdx.x;
  bool doh = blockIdx.x < 256;                         // block-uniform
  if (doh && tid < 128) gc[tid] = 0.f;
  __syncthreads();
  int idx = blockIdx.x * 256 + tid;
  int gstr = gridDim.x * 256;
  for (int e = idx; e < E; e += gstr){
    int s = ei[e], d = ei[E + e];
    int pos = atomicAdd(cur + d, 1);
    if (pos < PAD) csr_src[(size_t)d * PAD + pos] = s; // guard impossible overflow
  }
  if (doh){
    for (int n = idx; n < N; n += 256 * 256)
      atomicAdd(&gc[batch[n]], 1.f);
    __syncthreads();
    if (tid < 128 && gc[tid] != 0.f) atomicAdd(gcnt + tid, gc[tid]);
  }
}

// ---- Fused layer 1: edge accumulation (linearity trick) + out1 + h2 + L2 logits
// phase 1: 8 lanes/node; rounds 1 AND 2 speculatively preloaded above the PQ
//   barrier (P(wave needs round 2) ~ 0.91 -- the serial 2nd-round chain was the
//   hidden cost, R8). PQ preamble parallelized across all 256 threads (was one
//   wave x 32 scalar loads while 3 waves idled at the barrier).
// phase 2: out1 f16 in LDS [32][136]; h2 = out1 @ W2 via 4x mfma_f32_16x16x32_f16
// NOTE: min-waves 6 (not 8): 8 forces a 64-VGPR budget -> scratch spill (R15).
__global__ void __launch_bounds__(256, 6)
k_layer1(const int* __restrict__ degp, const int* __restrict__ csr_src,
         const float* __restrict__ x, const float* __restrict__ W1,
         const float* __restrict__ as1, const float* __restrict__ ad1,
         const float* __restrict__ b1, const float* __restrict__ W2,
         const float* __restrict__ as2, const float* __restrict__ ad2,
         __half* __restrict__ h2h, float* __restrict__ als2,
         float* __restrict__ ald2, int N){
  __shared__ float PQ[2][16];                          // [which][k*4+h]
  __shared__ __align__(16) float xa[32][20];           // per-node {acc[16], rs[4]}
  __shared__ __align__(16) _Float16 out1sh[32][136];   // pad 8 halfs: 272B row -> 2-way on b128
  __shared__ __align__(16) float h2sh[32][36];         // f32 h2 tile (pad for b128 align)
  __shared__ float als_s[32], ald_s[32];               // staged L2-logit outputs
  int tid = threadIdx.x;
  const float4* x4 = (const float4*)x;

  // ---- speculative loads for rounds 1+2 (before PQ compute + barrier) ----
  int g1 = tid >> 3, l = tid & 7;
  int node1 = blockIdx.x * 32 + g1;
  int nd = node1 < N ? node1 : N - 1;
  int deg = degp[nd];                                  // load A
  size_t r0 = (size_t)nd * PAD;
  int s_pre  = csr_src[r0 + l];                        // round-1 csr (indep of A)
  int s_pre2 = csr_src[r0 + 8 + l];                    // round-2 csr: SAME 128B line
  int total = (node1 < N) ? deg + 1 : 0;
  int s0 = (l < deg)     ? s_pre  : nd;                // sanitize poison beyond deg
  int s1 = (8 + l < deg) ? s_pre2 : nd;
  float4 xv0 = x4[s0];                                 // round-1 gather
  float4 xv1 = x4[s1];                                 // round-2 gather (91% of waves)
  float4 xn  = x4[nd];

  // ---- PQ preamble: all 256 threads (was 32 lanes of wave 0) ----
  {
    int kh2 = tid >> 3, j = tid & 7;                   // output kh2, 4-term slice j
    int which = kh2 >> 4, kh = kh2 & 15, k = kh >> 2, h = kh & 3;
    const float* a = which ? ad1 : as1;
    float4 wv = *(const float4*)(W1 + k*128 + h*32 + j*4);
    float4 av = *(const float4*)(a + h*32 + j*4);
    float s = wv.x*av.x + wv.y*av.y + wv.z*av.z + wv.w*av.w;
    s += __shfl_xor(s, 1, 8);
    s += __shfl_xor(s, 2, 8);
    s += __shfl_xor(s, 4, 8);
    if (j == 0) PQ[which][kh] = s;
  }
  __syncthreads();

  // ---- phase 1: 8 lanes per node ----
  {
    float P[16], Q[16];
    #pragma unroll
    for (int i = 0; i < 16; i++){ P[i] = PQ[0][i]; Q[i] = PQ[1][i]; }
    float ald0  = xn.x*Q[0] + xn.y*Q[4] + xn.z*Q[8]  + xn.w*Q[12];
    float ald1_ = xn.x*Q[1] + xn.y*Q[5] + xn.z*Q[9]  + xn.w*Q[13];
    float ald2_ = xn.x*Q[2] + xn.y*Q[6] + xn.z*Q[10] + xn.w*Q[14];
    float ald3  = xn.x*Q[3] + xn.y*Q[7] + xn.z*Q[11] + xn.w*Q[15];
    float acc[16];
    #pragma unroll
    for (int i = 0; i < 16; i++) acc[i] = 0.f;
    float ss[4] = {0.f, 0.f, 0.f, 0.f};
    auto edge = [&](float4 xv){
      float a0 = xv.x*P[0] + xv.y*P[4] + xv.z*P[8]  + xv.w*P[12];
      float a1 = xv.x*P[1] + xv.y*P[5] + xv.z*P[9]  + xv.w*P[13];
      float a2 = xv.x*P[2] + xv.y*P[6] + xv.z*P[10] + xv.w*P[14];
      float a3 = xv.x*P[3] + xv.y*P[7] + xv.z*P[11] + xv.w*P[15];
      float e0 = __expf(lrelu(a0 + ald0));
      float e1 = __expf(lrelu(a1 + ald1_));
      float e2 = __expf(lrelu(a2 + ald2_));
      float e3 = __expf(lrelu(a3 + ald3));
      ss[0] += e0; ss[1] += e1; ss[2] += e2; ss[3] += e3;
      acc[0]  += e0*xv.x; acc[1]  += e0*xv.y; acc[2]  += e0*xv.z; acc[3]  += e0*xv.w;
      acc[4]  += e1*xv.x; acc[5]  += e1*xv.y; acc[6]  += e1*xv.z; acc[7]  += e1*xv.w;
      acc[8]  += e2*xv.x; acc[9]  += e2*xv.y; acc[10] += e2*xv.z; acc[11] += e2*xv.w;
      acc[12] += e3*xv.x; acc[13] += e3*xv.y; acc[14] += e3*xv.z; acc[15] += e3*xv.w;
    };
    if (l < total)     edge(xv0);                      // round 1: preloaded
    if (8 + l < total) edge(xv1);                      // round 2: preloaded (R8)
    for (int t = l + 16; t < total; t += 8){           // P(deg>=16) ~ 1e-3
      int s = (t < deg) ? csr_src[r0 + t] : nd;
      edge(x4[s]);
    }
    #pragma unroll
    for (int m = 4; m >= 1; m >>= 1){
      #pragma unroll
      for (int i = 0; i < 16; i++) acc[i] += __shfl_xor(acc[i], m, 8);
      #pragma unroll
      for (int i = 0; i < 4; i++)  ss[i]  += __shfl_xor(ss[i], m, 8);
    }
    if (l == 0){
      float* o = xa[g1];
      *(float4*)(o)      = make_float4(acc[0],  acc[1],  acc[2],  acc[3]);
      *(float4*)(o + 4)  = make_float4(acc[4],  acc[5],  acc[6],  acc[7]);
      *(float4*)(o + 8)  = make_float4(acc[8],  acc[9],  acc[10], acc[11]);
      *(float4*)(o + 12) = make_float4(acc[12], acc[13], acc[14], acc[15]);
      *(float4*)(o + 16) = make_float4(ss[0], ss[1], ss[2], ss[3]);
    }
  }
  __syncthreads();
  // cooperative reciprocal: one IEEE div per (node, head) instead of 16x per thread
  if (tid < 128) xa[tid >> 2][16 + (tid & 3)] = 1.f / xa[tid >> 2][16 + (tid & 3)];
  __builtin_amdgcn_sched_barrier(0);   // keep phase-2 weight loads below phase 1

  // ---- phase-2 constants: live range starts after phase 1 (no spill) ----
  int wv = tid >> 6, lane = tid & 63;
  int wm = wv >> 1, wn = wv & 1;                      // wave's 16x16 output tile
  int lrow = lane & 15, lk8 = lane >> 4;              // frag row/col + k-octet
  // B fragments: W2[k][n], lane holds k = t*32 + lk8*8 + j, n = wn*16 + lrow
  half8 bf[4];
  #pragma unroll
  for (int t = 0; t < 4; t++){
    #pragma unroll
    for (int j = 0; j < 8; j++)
      bf[t][j] = (_Float16)W2[(t*32 + lk8*8 + j)*32 + wn*16 + lrow];
  }
  // out1 weights: thread owns channel c128 for 16 nodes
  int c128 = ((wv & 1) << 6) | lane;                  // 0..127
  int gbase = (wv >> 1) << 4;                         // nodes gbase..gbase+15
  int hh = c128 >> 5;                                 // head of this channel
  float w1c0 = W1[c128], w1c1 = W1[128 + c128];
  float w1c2 = W1[256 + c128], w1c3 = W1[384 + c128];
  float b1c = b1[c128];
  __syncthreads();                                    // rcp fixup visible

  // ---- phase 2a: out1 = elu((xa . W1) * rs + b1) for all 32 nodes -> LDS f16 ----
  #pragma unroll
  for (int i = 0; i < 16; i++){
    int g = gbase + i;
    const float* xg = xa[g];
    float4 xv = *(const float4*)(xg + hh*4);          // broadcast LDS
    float rs = xg[16 + hh];
    float o = elu1((xv.x*w1c0 + xv.y*w1c1 + xv.z*w1c2 + xv.w*w1c3) * rs + b1c);
    out1sh[g][c128] = (_Float16)o;
  }
  __syncthreads();

  // ---- phase 2b: h2 = out1 @ W2 via MFMA (M=32, N=32, K=128) ----
  {
    f32x4 acc2 = {0.f, 0.f, 0.f, 0.f};
    #pragma unroll
    for (int t = 0; t < 4; t++){
      half8 af = *(const half8*)(&out1sh[wm*16 + lrow][t*32 + lk8*8]);
      acc2 = __builtin_amdgcn_mfma_f32_16x16x32_f16(af, bf[t], acc2, 0, 0, 0);
    }
    // C/D layout: col = lane&15, row = (lane>>4)*4 + i
    #pragma unroll
    for (int i = 0; i < 4; i++)
      h2sh[wm*16 + lk8*4 + i][wn*16 + lrow] = acc2[i];
  }
  __syncthreads();

  // ---- epilogue: h2h f16 store + L2 logits (8 lanes per node) ----
  {
    int g = tid >> 3, q = tid & 7;                    // node g, channels 4q..4q+3
    int node = blockIdx.x * 32 + g;
    float4 hv = *(const float4*)(&h2sh[g][q*4]);
    if (node < N){
      __half2 pa = __floats2half2_rn(hv.x, hv.y);
      __half2 pb = __floats2half2_rn(hv.z, hv.w);
      __half2* dst = (__half2*)(h2h + (size_t)node*32 + q*4);
      dst[0] = pa; dst[1] = pb;
    }
    float4 sa = *(const float4*)(as2 + q*4);
    float4 da = *(const float4*)(ad2 + q*4);
    float ps = hv.x*sa.x + hv.y*sa.y + hv.z*sa.z + hv.w*sa.w;
    float pd = hv.x*da.x + hv.y*da.y + hv.z*da.z + hv.w*da.w;
    #pragma unroll
    for (int m = 4; m >= 1; m >>= 1){
      ps += __shfl_xor(ps, m, 8);
      pd += __shfl_xor(pd, m, 8);
    }
    if (q == 0){ als_s[g] = ps; ald_s[g] = pd; }      // stage in LDS
  }
  __syncthreads();
  if (tid < 32){
    int node = blockIdx.x * 32 + tid;
    if (node < N){ als2[node] = als_s[tid]; ald2[node] = ald_s[tid]; }
  }
}

// ---- Layer 2 gather + pool partials: champion structure, guard-free rounds ----
// block 256 = 8 nodes x 32 lanes; c2 = lane&15 -> channels 2c2,2c2+1;
// sub = lane>>4 picks which edge of each pair. Full 8-edge rounds, no guards:
// lanes past total hold ex=0 / s=node (safe self-row); base steps by 32 so
// jj<=24 -> all shuffle indices <=31. Falsified theories (R3-R7): issue count,
// global atomics (R5), MLP depth (R6), als/h2 line co-location (R7) -- all flat.
// NO device fences (R17: per-block fence = 935us).
__global__ void __launch_bounds__(256)
k_gat2(const int* __restrict__ degp, const int* __restrict__ csr_src,
       const __half* __restrict__ h2h, const float* __restrict__ als2,
       const float* __restrict__ ald2, const float* __restrict__ b2,
       const int* __restrict__ batch, float* __restrict__ gsum_part, int N){
  int tid = threadIdx.x;
  int node = blockIdx.x * 8 + (tid >> 5);
  if (node >= N) return;
  int lane = tid & 31;
  int c2 = lane & 15;                                  // channel pair: 2c2, 2c2+1
  int sub = lane >> 4;                                 // which edge of the pair
  int deg = degp[node];
  size_t r0 = (size_t)node * PAD;
  int total = deg + 1;
  float ald = ald2[node];

  float ssum = 0.f;
  float f0 = 0.f, f1 = 0.f, f2 = 0.f, f3 = 0.f;
  for (int base = 0; base < total; base += 32){
    int t = base + lane;
    int s = (t < deg) ? csr_src[r0 + t] : node;
    float ex = (t < total) ? __expf(lrelu(als2[s] + ald)) : 0.f;
    ssum += ex;
    int lim = min(32, total - base);
    for (int jj = 0; jj < lim; jj += 8){               // full 8-edge rounds, no guards
      int ja = jj + sub,     jb = jj + 2 + sub;        // all indices <= 31 (jj <= 24)
      int jc = jj + 4 + sub, jd = jj + 6 + sub;
      float ea = __shfl(ex, ja, 32); int sa = __shfl(s, ja, 32);
      float eb = __shfl(ex, jb, 32); int sb = __shfl(s, jb, 32);
      float ec = __shfl(ex, jc, 32); int sc = __shfl(s, jc, 32);
      float ed = __shfl(ex, jd, 32); int sd = __shfl(s, jd, 32);
      float2 va = __half22float2(*(const __half2*)(h2h + (size_t)sa*32 + 2*c2));
      float2 vb = __half22float2(*(const __half2*)(h2h + (size_t)sb*32 + 2*c2));
      float2 vc = __half22float2(*(const __half2*)(h2h + (size_t)sc*32 + 2*c2));
      float2 vd = __half22float2(*(const __half2*)(h2h + (size_t)sd*32 + 2*c2));
      f0 += ea*va.x + eb*vb.x;
      f1 += ea*va.y + eb*vb.y;
      f2 += ec*vc.x + ed*vd.x;
      f3 += ec*vc.y + ed*vd.y;
    }
  }
  float fx = f0 + f2, fy = f1 + f3;
  fx += __shfl_xor(fx, 16, 32);                        // combine sub halves
  fy += __shfl_xor(fy, 16, 32);
  #pragma unroll
  for (int m = 16; m >= 1; m >>= 1) ssum += __shfl_xor(ssum, m, 32);
  // lane -> channel 2*c2+sub: each of 32 lanes writes exactly one channel
  float fc = sub ? fy : fx;
  int ch = 2*c2 + sub;
  float v = elu1(fc / ssum + b2[ch]);
  int b = batch[node];
  atomicAdd(gsum_part + ((blockIdx.x & (NPART-1)) << 12) + b*32 + ch, v);
}

// ---- MLP head: reduce partials + divide + 2-layer MLP ----
__global__ void k_head(const float* __restrict__ gsum_part, const float* __restrict__ gcnt,
                       const float* __restrict__ Wc1, const float* __restrict__ bc1,
                       const float* __restrict__ Wc2, const float* __restrict__ bc2,
                       float* __restrict__ out){
  int g = blockIdx.x, tid = threadIdx.x;
  __shared__ float gl[32];
  if (tid < 32){
    float s = 0.f;
    #pragma unroll
    for (int p = 0; p < NPART; p++) s += gsum_part[(p << 12) + g*32 + tid];
    float cnt = gcnt[g];
    cnt = cnt > 1.f ? cnt : 1.f;
    gl[tid] = s / cnt;
  }
  __syncthreads();
  if (tid < 32){
    float z = bc1[tid];
    #pragma unroll 8
    for (int c2 = 0; c2 < 32; c2++) z += gl[c2] * Wc1[c2*32 + tid];
    z = z > 0.f ? z : 0.f;
    float r = z * Wc2[tid];
    #pragma unroll
    for (int m = 16; m >= 1; m >>= 1) r += __shfl_xor(r, m, 32);
    if (tid == 0) out[g] = 1.f / (1.f + expf(-(r + bc2[0])));
  }
}

extern "C" void kernel_launch(void* const* d_in, const int* in_sizes, int n_in,
                              void* d_out, int out_size, void* d_ws, size_t ws_size,
                              hipStream_t stream){
  const float* x   = (const float*)d_in[0];
  const int*   ei  = (const int*)d_in[1];
  const int*   bat = (const int*)d_in[2];
  const float* W1  = (const float*)d_in[3];
  const float* as1 = (const float*)d_in[4];
  const float* ad1 = (const float*)d_in[5];
  const float* b1  = (const float*)d_in[6];
  const float* W2  = (const float*)d_in[7];
  const float* as2 = (const float*)d_in[8];
  const float* ad2 = (const float*)d_in[9];
  const float* b2  = (const float*)d_in[10];
  const float* Wc1 = (const float*)d_in[11];
  const float* bc1 = (const float*)d_in[12];
  const float* Wc2 = (const float*)d_in[13];
  const float* bc2 = (const float*)d_in[14];
  float* out = (float*)d_out;

  const int N = in_sizes[2];
  const int E = in_sizes[1] / 2;

  float* ws = (float*)d_ws;
  size_t off = 0;
  // zero-init region (single memset): cur + gsum_part + gcnt
  int* cur    = (int*)ws;           off += (size_t)N;        // becomes deg after k_scat
  float* gsum_part = ws + off;      off += (size_t)NPART * 4096;
  float* gcnt = ws + off;           off += 128;
  const size_t zero_elems = off;
  __half* h2h = (__half*)(ws + off); off += (size_t)N * 16;  // N*32 halfs
  float* als2 = ws + off;           off += (size_t)N;
  float* ald2 = ws + off;           off += (size_t)N;
  int* csr_src= (int*)(ws + off);   off += (size_t)N * PAD;  // 128B-aligned rows

  hipMemsetAsync(d_ws, 0, zero_elems * sizeof(float), stream);

  // padded-CSR build + gcnt histogram (fused, single edge pass)
  k_scat<<<(E + 255) / 256, 256, 0, stream>>>(ei, bat, cur, csr_src, gcnt, N, E);

  // fused layer 1 (+ h2 f16 + layer-2 logits)
  k_layer1<<<(N + 31) / 32, 256, 0, stream>>>(cur, csr_src, x, W1, as1, ad1, b1,
                                              W2, as2, ad2, h2h, als2, ald2, N);

  // layer 2 gather + fused pool partials
  k_gat2<<<(N + 7) / 8, 256, 0, stream>>>(cur, csr_src, h2h, als2, ald2, b2,
                                          bat, gsum_part, N);

  // head (reduces partials)
  k_head<<<128, 64, 0, stream>>>(gsum_part, gcnt, Wc1, bc1, Wc2, bc2, out);
}